// Round 6
// baseline (448.267 us; speedup 1.0000x reference)
//
#include <hip/hip_runtime.h>
#include <hip/hip_bf16.h>
#include <math.h>

#define NS 255
#define NB 64
#define NE 200
#define NH 300
#define TS 2048          // shorts per 4KB tile (64 rows x 32 k)
#define NBLK 256

// ws layout (bytes):
//  HbfT  [255][10][TS] bf16 tiled/swizzled  @ 0           (10,444,800)
//  C     [255*64][300] f32                  @ 10,444,800  (19,584,000)
//  AembT [255][7][TS] bf16 tiled/swizzled   @ 30,028,800  ( 7,311,360)
//  BW    [4][5][17][TS] bf16 tiled/swizzled @ 37,340,160  ( 1,392,640)
//  bar   [16] int grid-barrier counters     @ 38,732,800  (        64)
//  end 38,732,864 (< 39,168,064 proven available in R3/R4)

typedef __attribute__((ext_vector_type(8))) short short8;
typedef __attribute__((ext_vector_type(4))) float f32x4;

__device__ __forceinline__ float sigmoidf_(float x) { return 1.0f / (1.0f + __expf(-x)); }
__device__ __forceinline__ unsigned short f2bf(float v) {
    union { __hip_bfloat16 b; unsigned short u; } cv; cv.b = __float2bfloat16(v); return cv.u;
}
__device__ __forceinline__ float bf2f(unsigned short u) {
    union { unsigned short u; __hip_bfloat16 b; } cv; cv.u = u; return __bfloat162float(cv.b);
}
// swizzled element offset (shorts) within a 64x32 tile
__device__ __forceinline__ int swz(int row, int kk) {
    int g = (kk >> 3) ^ ((row >> 1) & 3);
    return ((row << 2) + g) * 8 + (kk & 7);
}

// grid barrier: release-agent (writeback dirty L2, keep lines resident) +
// device-scope counter. No acquire-invalidate: every global line is written
// once and first-touched by any reader XCD afterwards, so stale copies are
// structurally impossible (see analysis). Co-residency: 256 blocks @48KB LDS
// = 1 block/CU needed vs 3/CU capacity.
__device__ __forceinline__ void gbar(int* c, int tid) {
    __syncthreads();
    if (tid == 0) {
        __builtin_amdgcn_fence(__ATOMIC_RELEASE, "agent");
        __hip_atomic_fetch_add(c, 1, __ATOMIC_RELAXED, __HIP_MEMORY_SCOPE_AGENT);
        while (__hip_atomic_load(c, __ATOMIC_RELAXED, __HIP_MEMORY_SCOPE_AGENT) < NBLK)
            __builtin_amdgcn_s_sleep(2);
    }
    __syncthreads();
}

// stage one 4KB tile: 4 issues of 64 lanes x 16B, lane-contiguous
__device__ __forceinline__ void stage_tile(const unsigned short* __restrict__ g,
                                           unsigned short* l, int lane)
{
#pragma unroll
    for (int i = 0; i < 4; ++i)
        __builtin_amdgcn_global_load_lds(
            (const __attribute__((address_space(1))) unsigned short*)(g + i * 512 + lane * 8),
            (__attribute__((address_space(3))) unsigned short*)(l + i * 512 + lane * 8),
            16, 0, 0);
}

// one K=32 chunk: A tile x B tile -> acc (64x64), fragments from swizzled LDS
__device__ __forceinline__ void mfma_chunk(f32x4 acc[4][4],
                                           const unsigned short* At,
                                           const unsigned short* Bt,
                                           int ln, int quad)
{
    short8 a0 = *(const short8*)(At + ((ln)      * 4 + (quad ^ (((ln)      >> 1) & 3))) * 8);
    short8 a1 = *(const short8*)(At + ((ln + 16) * 4 + (quad ^ (((ln + 16) >> 1) & 3))) * 8);
    short8 a2 = *(const short8*)(At + ((ln + 32) * 4 + (quad ^ (((ln + 32) >> 1) & 3))) * 8);
    short8 a3 = *(const short8*)(At + ((ln + 48) * 4 + (quad ^ (((ln + 48) >> 1) & 3))) * 8);
#pragma unroll
    for (int t = 0; t < 4; ++t) {
        int bc = ln + t * 16;
        short8 b = *(const short8*)(Bt + (bc * 4 + (quad ^ ((bc >> 1) & 3))) * 8);
        acc[t][0] = __builtin_amdgcn_mfma_f32_16x16x32_bf16(a0, b, acc[t][0], 0, 0, 0);
        acc[t][1] = __builtin_amdgcn_mfma_f32_16x16x32_bf16(a1, b, acc[t][1], 0, 0, 0);
        acc[t][2] = __builtin_amdgcn_mfma_f32_16x16x32_bf16(a2, b, acc[t][2], 0, 0, 0);
        acc[t][3] = __builtin_amdgcn_mfma_f32_16x16x32_bf16(a3, b, acc[t][3], 0, 0, 0);
    }
}

// process one (node p, strip s): 5-wave fused GEMM + gates. R4-proven body.
__device__ __forceinline__ void do_node(
    unsigned short* sm, int p, int s, int is_leaf, int tid,
    const unsigned short* __restrict__ AembT, const unsigned short* __restrict__ BW,
    const float* __restrict__ b_iou, const float* __restrict__ b_f,
    unsigned short* __restrict__ HbfT, float* __restrict__ C)
{
    int w = tid >> 6, lane = tid & 63, ln = lane & 15, quad = lane >> 4;
    int l = 2 * p + 1, r = 2 * p + 2;
    int bsel = (w < 4) ? w : 3;
    const unsigned short* Bsrc = BW + (size_t)(bsel * 5 + s) * 17 * TS;
    const unsigned short* Ae = AembT + (size_t)p * 7 * TS;
    const unsigned short* Hl = HbfT + (size_t)l * 10 * TS;
    const unsigned short* Hr = HbfT + (size_t)r * 10 * TS;
    int ctot = is_leaf ? 7 : 17;

    f32x4 acc[4][4];
#pragma unroll
    for (int t = 0; t < 4; ++t)
#pragma unroll
        for (int q = 0; q < 4; ++q) acc[t][q] = (f32x4){0.f, 0.f, 0.f, 0.f};

    auto stage = [&](int c, int buf) {
        unsigned short* bb = sm + buf * 6 * TS;
        if (c < 7) {
            if (w < 4) stage_tile(Bsrc + (size_t)c * TS, bb + (2 + w) * TS, lane);
            else       stage_tile(Ae + (size_t)c * TS, bb, lane);
        } else {
            int hc = c - 7;
            if (w < 3)       stage_tile(Bsrc + (size_t)c * TS, bb + (2 + w) * TS, lane);
            else if (w == 3) { stage_tile(Bsrc + (size_t)c * TS, bb + 5 * TS, lane);
                               stage_tile(Hl + (size_t)hc * TS, bb, lane); }
            else             stage_tile(Hr + (size_t)hc * TS, bb + TS, lane);
        }
    };
    auto compute = [&](int c, int buf) {
        unsigned short* bb = sm + buf * 6 * TS;
        const unsigned short* Bt = bb + (2 + bsel) * TS;
        if (c < 7) {
            mfma_chunk(acc, bb, Bt, ln, quad);
        } else if (w < 3) {
            mfma_chunk(acc, bb, Bt, ln, quad);
            mfma_chunk(acc, bb + TS, Bt, ln, quad);
        } else if (w == 3) {
            mfma_chunk(acc, bb, Bt, ln, quad);
        } else {
            mfma_chunk(acc, bb + TS, Bt, ln, quad);
        }
    };

    stage(0, 0);
    for (int c = 0; c < ctot; ++c) {
        int cur = c & 1;
        __syncthreads();                       // drains stage(c); frees buf cur^1
        if (c + 1 < ctot) stage(c + 1, cur ^ 1);
        compute(c, cur);
    }

    // epilogue: exchange through LDS, fused gates + cell update
    float* tile = (float*)sm;                  // 5*64*16 f32 = 20 KB
    for (int t = 0; t < 4; ++t) {
        __syncthreads();
#pragma unroll
        for (int ms = 0; ms < 4; ++ms)
#pragma unroll
            for (int rr = 0; rr < 4; ++rr)
                tile[(w * 64 + ms * 16 + quad * 4 + rr) * 16 + ln] = acc[t][ms][rr];
        __syncthreads();
        for (int idx = tid; idx < 1024; idx += 320) {
            int m = idx >> 4, n = idx & 15;
            int jj = s * 64 + t * 16 + n;      // 0..319
            bool ok = jj < NH;
            float pi = tile[(0 * 64 + m) * 16 + n] + (ok ? b_iou[jj] : 0.f);
            float po = tile[(1 * 64 + m) * 16 + n] + (ok ? b_iou[NH + jj] : 0.f);
            float pu = tile[(2 * 64 + m) * 16 + n] + (ok ? b_iou[2 * NH + jj] : 0.f);
            float cc;
            if (is_leaf) {
                cc = sigmoidf_(pi) * tanhf(pu);
            } else {
                float bj = ok ? b_f[jj] : 0.f;
                float fl = sigmoidf_(tile[(3 * 64 + m) * 16 + n] + bj);
                float fr = sigmoidf_(tile[(4 * 64 + m) * 16 + n] + bj);
                float cl = ok ? C[((size_t)l * NB + m) * NH + jj] : 0.f;
                float cr = ok ? C[((size_t)r * NB + m) * NH + jj] : 0.f;
                cc = sigmoidf_(pi) * tanhf(pu) + fl * cl + fr * cr;
            }
            float hh = sigmoidf_(po) * tanhf(cc);
            if (ok) C[((size_t)p * NB + m) * NH + jj] = cc;
            HbfT[((size_t)p * 10 + (jj >> 5)) * TS + swz(m, jj & 31)]
                = ok ? f2bf(hh) : (unsigned short)0;
        }
    }
}

// ---------------- single fused kernel (plain launch + manual grid barrier) --
// 256 blocks. xcd = bid & 7 (round-robin hypothesis; perf-only), jb = bid>>3.
// Level d>=3: nodes i = xcd*2^(d-3) + o  -> whole subtrees stay on one XCD.
// Level d<3: node i on xcd i<<(3-d), strips on blocks jb=0..4.
__global__ __launch_bounds__(320) void fused_kernel(
    const float* __restrict__ U_iou, const float* __restrict__ U_f,
    const float* __restrict__ W_iou, const float* __restrict__ W_f,
    const float* __restrict__ embed, const int* __restrict__ x,
    const float* __restrict__ b_iou, const float* __restrict__ b_f,
    const float* __restrict__ W_out, const float* __restrict__ b_out,
    unsigned short* __restrict__ BW, unsigned short* __restrict__ AembT,
    unsigned short* __restrict__ HbfT, float* __restrict__ C,
    float* __restrict__ out, int* __restrict__ bar)
{
    __shared__ unsigned short sm[12 * TS];   // 48 KB
    int bid = blockIdx.x;
    int tid = threadIdx.x;

    // ---- phase 0: prep (weights tile/transpose/bf16, emb gather) ----
    {
        const int nBW = 4 * 5 * 17 * TS;   // 696320
        const int nAe = NS * 7 * TS;       // 3655680
        int total = nBW + nAe;
        int stride = gridDim.x * blockDim.x;
        for (int i = bid * blockDim.x + tid; i < total; i += stride) {
            if (i < nBW) {
                int e = i & (TS - 1), tile = i >> 11;
                int c = tile % 17, t2 = tile / 17;
                int st = t2 % 5, g = t2 / 5;
                int row = e >> 5, pos = (e >> 3) & 3;
                int kk = ((pos ^ ((row >> 1) & 3)) << 3) + (e & 7);
                int j = st * 64 + row;
                float v = 0.f;
                if (c < 7) {
                    int k = c * 32 + kk;
                    if (j < NH && k < NE) v = (g < 3) ? W_iou[k * 900 + g * NH + j] : W_f[k * NH + j];
                } else {
                    int k = (c - 7) * 32 + kk;
                    if (j < NH && k < NH) v = (g < 3) ? U_iou[k * 900 + g * NH + j] : U_f[k * NH + j];
                }
                BW[i] = f2bf(v);
            } else {
                int i2 = i - nBW;
                int e = i2 & (TS - 1), tile = i2 >> 11;
                int c = tile % 7, node = tile / 7;
                int row = e >> 5, pos = (e >> 3) & 3;    // row = batch b
                int kk = ((pos ^ ((row >> 1) & 3)) << 3) + (e & 7);
                int k = c * 32 + kk;
                float v = 0.f;
                if (k < NE) v = embed[(size_t)x[node * NB + row] * NE + k];
                AembT[i2] = f2bf(v);
            }
        }
    }
    gbar(bar + 0, tid);

    int xcd = bid & 7, jb = bid >> 3;
    int bi = 1;

    // ---- levels 7..3: subtree-local on one XCD ----
    for (int d = 7; d >= 3; --d) {
        int base = (1 << d) - 1;
        int m = 1 << (d - 3);
        for (int tt = jb; tt < m * 5; tt += 32) {
            int o = tt / 5, s = tt % 5;
            do_node(sm, base + xcd * m + o, s, d == 7 ? 1 : 0, tid,
                    AembT, BW, b_iou, b_f, HbfT, C);
        }
        gbar(bar + bi++, tid);
    }
    // ---- levels 2..0 ----
    for (int d = 2; d >= 0; --d) {
        int sh = 3 - d;
        if (jb < 5 && (xcd & ((1 << sh) - 1)) == 0) {
            int i = xcd >> sh;
            do_node(sm, (1 << d) - 1 + i, jb, 0, tid,
                    AembT, BW, b_iou, b_f, HbfT, C);
        }
        gbar(bar + bi++, tid);
    }

    // ---- out: root -> logits -> log_softmax ----
    if (bid == 0 && tid < NB) {
        int b = tid;
        float l0 = 0.f, l1 = 0.f;
#pragma unroll 4
        for (int k = 0; k < NH; ++k) {
            float hk = bf2f(HbfT[(size_t)(k >> 5) * TS + swz(b, k & 31)]);
            l0 += hk * W_out[k * 2];
            l1 += hk * W_out[k * 2 + 1];
        }
        l0 += b_out[0];
        l1 += b_out[1];
        float mx = fmaxf(l0, l1);
        float lse = mx + logf(__expf(l0 - mx) + __expf(l1 - mx));
        out[b * 2 + 0] = l0 - lse;
        out[b * 2 + 1] = l1 - lse;
    }
}

extern "C" void kernel_launch(void* const* d_in, const int* in_sizes, int n_in,
                              void* d_out, int out_size, void* d_ws, size_t ws_size,
                              hipStream_t stream)
{
    const int*   x     = (const int*)d_in[0];
    const float* embed = (const float*)d_in[3];
    const float* W_iou = (const float*)d_in[4];
    const float* U_iou = (const float*)d_in[5];
    const float* b_iou = (const float*)d_in[6];
    const float* W_f   = (const float*)d_in[7];
    const float* U_f   = (const float*)d_in[8];
    const float* b_f   = (const float*)d_in[9];
    const float* W_out = (const float*)d_in[10];
    const float* b_out = (const float*)d_in[11];

    char* ws = (char*)d_ws;
    unsigned short* HbfT  = (unsigned short*)(ws + 0);
    float*          C     = (float*)(ws + 10444800);
    unsigned short* AembT = (unsigned short*)(ws + 30028800);
    unsigned short* BW    = (unsigned short*)(ws + 37340160);
    int*            bar   = (int*)(ws + 38732800);

    hipMemsetAsync(bar, 0, 64, stream);
    fused_kernel<<<NBLK, 320, 0, stream>>>(U_iou, U_f, W_iou, W_f, embed, x,
                                           b_iou, b_f, W_out, b_out,
                                           BW, AembT, HbfT, C,
                                           (float*)d_out, bar);
}

// Round 7
// 354.658 us; speedup vs baseline: 1.2639x; 1.2639x over previous
//
#include <hip/hip_runtime.h>
#include <hip/hip_bf16.h>
#include <math.h>

#define NS 255
#define NB 64
#define NE 200
#define NH 300
#define TS 2048          // shorts per 4KB tile (64 rows x 32 k)

// ws layout (bytes):
//  HbfT  [255][10][TS] bf16 tiled/swizzled  @ 0           (10,444,800)
//  C     [255*64][300] f32                  @ 10,444,800  (19,584,000)
//  AembT [255][7][TS] bf16 tiled/swizzled   @ 30,028,800  ( 7,311,360)
//  BW    [4][5][17][TS] bf16 tiled/swizzled @ 37,340,160  ( 1,392,640)
//  end 38,732,800 (< 39,168,064 proven available)

typedef __attribute__((ext_vector_type(8))) short short8;
typedef __attribute__((ext_vector_type(4))) float f32x4;

__device__ __forceinline__ float sigmoidf_(float x) { return 1.0f / (1.0f + __expf(-x)); }
__device__ __forceinline__ unsigned short f2bf(float v) {
    union { __hip_bfloat16 b; unsigned short u; } cv; cv.b = __float2bfloat16(v); return cv.u;
}
__device__ __forceinline__ float bf2f(unsigned short u) {
    union { unsigned short u; __hip_bfloat16 b; } cv; cv.u = u; return __bfloat162float(cv.b);
}
// swizzled element offset (shorts) within a 64x32 tile
__device__ __forceinline__ int swz(int row, int kk) {
    int g = (kk >> 3) ^ ((row >> 1) & 3);
    return ((row << 2) + g) * 8 + (kk & 7);
}

// ---------------- prep: pre-tile weights + embeddings (R4-proven) -----------
__global__ __launch_bounds__(256) void prep_kernel(
    const float* __restrict__ U_iou, const float* __restrict__ U_f,
    const float* __restrict__ W_iou, const float* __restrict__ W_f,
    const float* __restrict__ embed, const int* __restrict__ x,
    unsigned short* __restrict__ BW, unsigned short* __restrict__ AembT)
{
    const int nBW = 4 * 5 * 17 * TS;   // 696320
    const int nAe = NS * 7 * TS;       // 3655680
    int total = nBW + nAe;
    int stride = gridDim.x * blockDim.x;
    for (int i = blockIdx.x * blockDim.x + threadIdx.x; i < total; i += stride) {
        if (i < nBW) {
            int e = i & (TS - 1), tile = i >> 11;
            int c = tile % 17, t2 = tile / 17;
            int s = t2 % 5, g = t2 / 5;
            int row = e >> 5, pos = (e >> 3) & 3;
            int kk = ((pos ^ ((row >> 1) & 3)) << 3) + (e & 7);
            int j = s * 64 + row;
            float v = 0.f;
            if (c < 7) {
                int k = c * 32 + kk;
                if (j < NH && k < NE) v = (g < 3) ? W_iou[k * 900 + g * NH + j] : W_f[k * NH + j];
            } else {
                int k = (c - 7) * 32 + kk;
                if (j < NH && k < NH) v = (g < 3) ? U_iou[k * 900 + g * NH + j] : U_f[k * NH + j];
            }
            BW[i] = f2bf(v);
        } else {
            int i2 = i - nBW;
            int e = i2 & (TS - 1), tile = i2 >> 11;
            int c = tile % 7, node = tile / 7;
            int row = e >> 5, pos = (e >> 3) & 3;    // row = batch b
            int kk = ((pos ^ ((row >> 1) & 3)) << 3) + (e & 7);
            int k = c * 32 + kk;
            float v = 0.f;
            if (k < NE) v = embed[(size_t)x[node * NB + row] * NE + k];
            AembT[i2] = f2bf(v);
        }
    }
}

// direct-from-global chunk loop: A[c][TS] x B[c][TS] -> acc, no LDS/barriers.
// off = lane's fragment offset (shorts); frag i of A at +512*i, tile t of B
// at +512*t (the swizzle's (row>>1)&3 term is invariant under row+16).
template<int NCH>
__device__ __forceinline__ void gemm_direct(f32x4 acc[4][4],
    const unsigned short* __restrict__ A, const unsigned short* __restrict__ B,
    int off)
{
#pragma unroll
    for (int c = 0; c < NCH; ++c) {
        const unsigned short* At = A + c * TS + off;
        const unsigned short* Bt = B + c * TS + off;
        short8 a0 = *(const short8*)(At);
        short8 a1 = *(const short8*)(At + 512);
        short8 a2 = *(const short8*)(At + 1024);
        short8 a3 = *(const short8*)(At + 1536);
#pragma unroll
        for (int t = 0; t < 4; ++t) {
            short8 b = *(const short8*)(Bt + t * 512);
            acc[t][0] = __builtin_amdgcn_mfma_f32_16x16x32_bf16(a0, b, acc[t][0], 0, 0, 0);
            acc[t][1] = __builtin_amdgcn_mfma_f32_16x16x32_bf16(a1, b, acc[t][1], 0, 0, 0);
            acc[t][2] = __builtin_amdgcn_mfma_f32_16x16x32_bf16(a2, b, acc[t][2], 0, 0, 0);
            acc[t][3] = __builtin_amdgcn_mfma_f32_16x16x32_bf16(a3, b, acc[t][3], 0, 0, 0);
        }
    }
}

// ---------------- per-level kernel: 5 waves = 5 gate-tasks of one (p,s) -----
// d>=3 (m=2^(d-3)>0): xcd=bid&7, idx=bid>>3, o=idx%m, s=idx/m, p=base+xcd*m+o
//   -> a node's 5 strips and its whole subtree stay on one XCD (perf only).
// d<3 (m==0): grid 40; xcd=bid&7 active if low sh bits clear; p=base+(xcd>>sh).
__global__ __launch_bounds__(320) void level_kernel(
    const unsigned short* __restrict__ AembT, const unsigned short* __restrict__ BW,
    const float* __restrict__ b_iou, const float* __restrict__ b_f,
    unsigned short* __restrict__ HbfT, float* __restrict__ C,
    int base, int m, int sh, int is_leaf)
{
    int bid = blockIdx.x;
    int p, s;
    if (m > 0) {
        int xcd = bid & 7, idx = bid >> 3;
        p = base + xcd * m + idx % m;
        s = idx / m;
    } else {
        int xcd = bid & 7;
        if (xcd & ((1 << sh) - 1)) return;
        p = base + (xcd >> sh);
        s = bid >> 3;
    }
    int tid = threadIdx.x;
    int w = tid >> 6, lane = tid & 63, ln = lane & 15, quad = lane >> 4;
    int l = 2 * p + 1, r = 2 * p + 2;
    int bsel = (w < 4) ? w : 3;
    int off = ln * 32 + (quad ^ ((ln >> 1) & 3)) * 8;

    const unsigned short* Bsrc = BW + (size_t)(bsel * 5 + s) * 17 * TS;
    const unsigned short* Ae = AembT + (size_t)p * 7 * TS;
    const unsigned short* Hl = HbfT + (size_t)l * 10 * TS;
    const unsigned short* Hr = HbfT + (size_t)r * 10 * TS;

    f32x4 acc[4][4];
#pragma unroll
    for (int t = 0; t < 4; ++t)
#pragma unroll
        for (int q = 0; q < 4; ++q) acc[t][q] = (f32x4){0.f, 0.f, 0.f, 0.f};

    if (w < 3) {
        gemm_direct<7>(acc, Ae, Bsrc, off);
        if (!is_leaf) {
            gemm_direct<10>(acc, Hl, Bsrc + 7 * TS, off);
            gemm_direct<10>(acc, Hr, Bsrc + 7 * TS, off);
        }
    } else if (!is_leaf) {
        gemm_direct<7>(acc, Ae, Bsrc, off);
        gemm_direct<10>(acc, (w == 3) ? Hl : Hr, Bsrc + 7 * TS, off);
    }

    // epilogue: exchange through LDS, fused gates + cell update (R4-proven)
    __shared__ float tile[5][64][16];          // 20 KB
    for (int t = 0; t < 4; ++t) {
        __syncthreads();
#pragma unroll
        for (int ms = 0; ms < 4; ++ms)
#pragma unroll
            for (int rr = 0; rr < 4; ++rr)
                tile[w][ms * 16 + quad * 4 + rr][ln] = acc[t][ms][rr];
        __syncthreads();
        for (int idx = tid; idx < 1024; idx += 320) {
            int mm = idx >> 4, n = idx & 15;
            int jj = s * 64 + t * 16 + n;      // 0..319
            bool ok = jj < NH;
            float pi = tile[0][mm][n] + (ok ? b_iou[jj] : 0.f);
            float po = tile[1][mm][n] + (ok ? b_iou[NH + jj] : 0.f);
            float pu = tile[2][mm][n] + (ok ? b_iou[2 * NH + jj] : 0.f);
            float cc;
            if (is_leaf) {
                cc = sigmoidf_(pi) * tanhf(pu);
            } else {
                float bj = ok ? b_f[jj] : 0.f;
                float fl = sigmoidf_(tile[3][mm][n] + bj);
                float fr = sigmoidf_(tile[4][mm][n] + bj);
                float cl = ok ? C[((size_t)l * NB + mm) * NH + jj] : 0.f;
                float cr = ok ? C[((size_t)r * NB + mm) * NH + jj] : 0.f;
                cc = sigmoidf_(pi) * tanhf(pu) + fl * cl + fr * cr;
            }
            float hh = sigmoidf_(po) * tanhf(cc);
            if (ok) C[((size_t)p * NB + mm) * NH + jj] = cc;
            HbfT[((size_t)p * 10 + (jj >> 5)) * TS + swz(mm, jj & 31)]
                = ok ? f2bf(hh) : (unsigned short)0;
        }
    }
}

// ---------------- root -> logits -> log_softmax -----------------------------
__global__ __launch_bounds__(64) void out_kernel(
    const unsigned short* __restrict__ HbfT,
    const float* __restrict__ W_out, const float* __restrict__ b_out,
    float* __restrict__ out)
{
    int b = threadIdx.x;
    float l0 = 0.f, l1 = 0.f;
#pragma unroll 4
    for (int k = 0; k < NH; ++k) {
        float hk = bf2f(HbfT[(size_t)(k >> 5) * TS + swz(b, k & 31)]);
        l0 += hk * W_out[k * 2];
        l1 += hk * W_out[k * 2 + 1];
    }
    l0 += b_out[0];
    l1 += b_out[1];
    float m = fmaxf(l0, l1);
    float lse = m + logf(__expf(l0 - m) + __expf(l1 - m));
    out[b * 2 + 0] = l0 - lse;
    out[b * 2 + 1] = l1 - lse;
}

extern "C" void kernel_launch(void* const* d_in, const int* in_sizes, int n_in,
                              void* d_out, int out_size, void* d_ws, size_t ws_size,
                              hipStream_t stream)
{
    const int*   x     = (const int*)d_in[0];
    const float* embed = (const float*)d_in[3];
    const float* W_iou = (const float*)d_in[4];
    const float* U_iou = (const float*)d_in[5];
    const float* b_iou = (const float*)d_in[6];
    const float* W_f   = (const float*)d_in[7];
    const float* U_f   = (const float*)d_in[8];
    const float* b_f   = (const float*)d_in[9];
    const float* W_out = (const float*)d_in[10];
    const float* b_out = (const float*)d_in[11];

    char* ws = (char*)d_ws;
    unsigned short* HbfT  = (unsigned short*)(ws + 0);
    float*          C     = (float*)(ws + 10444800);
    unsigned short* AembT = (unsigned short*)(ws + 30028800);
    unsigned short* BW    = (unsigned short*)(ws + 37340160);

    prep_kernel<<<4096, 256, 0, stream>>>(U_iou, U_f, W_iou, W_f, embed, x, BW, AembT);

    for (int d = 7; d >= 3; --d) {
        int base = (1 << d) - 1;
        int m = 1 << (d - 3);
        level_kernel<<<5 << d, 320, 0, stream>>>(AembT, BW, b_iou, b_f, HbfT, C,
                                                 base, m, 0, d == 7 ? 1 : 0);
    }
    for (int d = 2; d >= 0; --d) {
        level_kernel<<<40, 320, 0, stream>>>(AembT, BW, b_iou, b_f, HbfT, C,
                                             (1 << d) - 1, 0, 3 - d, 0);
    }
    out_kernel<<<1, 64, 0, stream>>>(HbfT, W_out, b_out, (float*)d_out);
}

// Round 8
// 289.151 us; speedup vs baseline: 1.5503x; 1.2266x over previous
//
#include <hip/hip_runtime.h>
#include <hip/hip_bf16.h>
#include <math.h>

#define NS 255
#define NB 64
#define NE 200
#define NH 300
#define TS 2048          // shorts per 4KB tile (64 rows x 32 k)

// ws layout (bytes):
//  HbfT  [255][10][TS] bf16 tiled/swizzled  @ 0           (10,444,800)
//  C     [255*64][300] f32                  @ 10,444,800  (19,584,000)
//  AembT [255][7][TS] bf16 tiled/swizzled   @ 30,028,800  ( 7,311,360)
//  BW    [4][5][17][TS] bf16 tiled/swizzled @ 37,340,160  ( 1,392,640)
//  end 38,732,800 (< 39,168,064 proven available)

typedef __attribute__((ext_vector_type(8))) short short8;
typedef __attribute__((ext_vector_type(4))) float f32x4;

__device__ __forceinline__ float sigmoidf_(float x) { return 1.0f / (1.0f + __expf(-x)); }
__device__ __forceinline__ unsigned short f2bf(float v) {
    union { __hip_bfloat16 b; unsigned short u; } cv; cv.b = __float2bfloat16(v); return cv.u;
}
__device__ __forceinline__ float bf2f(unsigned short u) {
    union { unsigned short u; __hip_bfloat16 b; } cv; cv.u = u; return __bfloat162float(cv.b);
}
// swizzled element offset (shorts) within a 64x32 tile
__device__ __forceinline__ int swz(int row, int kk) {
    int g = (kk >> 3) ^ ((row >> 1) & 3);
    return ((row << 2) + g) * 8 + (kk & 7);
}

// ---------------- prep: pre-tile weights + embeddings (R4-proven) -----------
__global__ __launch_bounds__(256) void prep_kernel(
    const float* __restrict__ U_iou, const float* __restrict__ U_f,
    const float* __restrict__ W_iou, const float* __restrict__ W_f,
    const float* __restrict__ embed, const int* __restrict__ x,
    unsigned short* __restrict__ BW, unsigned short* __restrict__ AembT)
{
    const int nBW = 4 * 5 * 17 * TS;   // 696320
    const int nAe = NS * 7 * TS;       // 3655680
    int total = nBW + nAe;
    int stride = gridDim.x * blockDim.x;
    for (int i = blockIdx.x * blockDim.x + threadIdx.x; i < total; i += stride) {
        if (i < nBW) {
            int e = i & (TS - 1), tile = i >> 11;
            int c = tile % 17, t2 = tile / 17;
            int s = t2 % 5, g = t2 / 5;
            int row = e >> 5, pos = (e >> 3) & 3;
            int kk = ((pos ^ ((row >> 1) & 3)) << 3) + (e & 7);
            int j = s * 64 + row;
            float v = 0.f;
            if (c < 7) {
                int k = c * 32 + kk;
                if (j < NH && k < NE) v = (g < 3) ? W_iou[k * 900 + g * NH + j] : W_f[k * NH + j];
            } else {
                int k = (c - 7) * 32 + kk;
                if (j < NH && k < NH) v = (g < 3) ? U_iou[k * 900 + g * NH + j] : U_f[k * NH + j];
            }
            BW[i] = f2bf(v);
        } else {
            int i2 = i - nBW;
            int e = i2 & (TS - 1), tile = i2 >> 11;
            int c = tile % 7, node = tile / 7;
            int row = e >> 5, pos = (e >> 3) & 3;    // row = batch b
            int kk = ((pos ^ ((row >> 1) & 3)) << 3) + (e & 7);
            int k = c * 32 + kk;
            float v = 0.f;
            if (k < NE) v = embed[(size_t)x[node * NB + row] * NE + k];
            AembT[i2] = f2bf(v);
        }
    }
}

// direct-from-global chunk loop, 32-row half: A frags 2, B frags 4, 8 MFMA.
template<int NCH>
__device__ __forceinline__ void gemm_h(f32x4 acc[4][2],
    const unsigned short* __restrict__ A, const unsigned short* __restrict__ B,
    int offA, int offB)
{
#pragma unroll
    for (int c = 0; c < NCH; ++c) {
        const unsigned short* At = A + c * TS + offA;
        const unsigned short* Bt = B + c * TS + offB;
        short8 a0 = *(const short8*)(At);
        short8 a1 = *(const short8*)(At + 512);
#pragma unroll
        for (int t = 0; t < 4; ++t) {
            short8 b = *(const short8*)(Bt + t * 512);
            acc[t][0] = __builtin_amdgcn_mfma_f32_16x16x32_bf16(a0, b, acc[t][0], 0, 0, 0);
            acc[t][1] = __builtin_amdgcn_mfma_f32_16x16x32_bf16(a1, b, acc[t][1], 0, 0, 0);
        }
    }
}

// ---------------- internal levels: 5 waves = 5 gate-tasks, 32-row half ------
// d>=3 (m>0): xcd=bid&7, idx=bid>>3: o=idx%m, rest=idx/m, s=rest%5, half=rest/5
// d<3 (m==0): grid 80; active if xcd low sh bits clear; p=base+(xcd>>sh).
__global__ __launch_bounds__(320) void level_kernel(
    const unsigned short* __restrict__ AembT, const unsigned short* __restrict__ BW,
    const float* __restrict__ b_iou, const float* __restrict__ b_f,
    unsigned short* __restrict__ HbfT, float* __restrict__ C,
    int base, int m, int sh)
{
    int bid = blockIdx.x;
    int p, s, half;
    if (m > 0) {
        int xcd = bid & 7, idx = bid >> 3;
        int o = idx % m, rest = idx / m;
        p = base + xcd * m + o;
        s = rest % 5; half = rest / 5;
    } else {
        int xcd = bid & 7;
        if (xcd & ((1 << sh) - 1)) return;
        p = base + (xcd >> sh);
        int idx = bid >> 3;
        s = idx % 5; half = idx / 5;
    }
    int tid = threadIdx.x;
    int w = tid >> 6, lane = tid & 63, ln = lane & 15, quad = lane >> 4;
    int l = 2 * p + 1, r = 2 * p + 2;
    int bsel = (w < 4) ? w : 3;
    int g = (quad ^ ((ln >> 1) & 3)) * 8;
    int offA = (half * 32 + ln) * 32 + g;    // (row>>1)&3 invariant under +16/+32
    int offB = ln * 32 + g;

    const unsigned short* Bsrc = BW + (size_t)(bsel * 5 + s) * 17 * TS;
    const unsigned short* Ae = AembT + (size_t)p * 7 * TS;
    const unsigned short* Hl = HbfT + (size_t)l * 10 * TS;
    const unsigned short* Hr = HbfT + (size_t)r * 10 * TS;

    f32x4 acc[4][2];
#pragma unroll
    for (int t = 0; t < 4; ++t)
#pragma unroll
        for (int q = 0; q < 2; ++q) acc[t][q] = (f32x4){0.f, 0.f, 0.f, 0.f};

    if (w < 3) {
        gemm_h<7>(acc, Ae, Bsrc, offA, offB);
        gemm_h<10>(acc, Hl, Bsrc + 7 * TS, offA, offB);
        gemm_h<10>(acc, Hr, Bsrc + 7 * TS, offA, offB);
    } else {
        gemm_h<7>(acc, Ae, Bsrc, offA, offB);
        gemm_h<10>(acc, (w == 3) ? Hl : Hr, Bsrc + 7 * TS, offA, offB);
    }

    // epilogue: exchange through padded LDS, fused gates + cell update
    __shared__ float tile[5][32][17];          // ~10.9 KB, 2-way max on banks
    for (int t = 0; t < 4; ++t) {
        __syncthreads();
#pragma unroll
        for (int ms = 0; ms < 2; ++ms)
#pragma unroll
            for (int rr = 0; rr < 4; ++rr)
                tile[w][ms * 16 + quad * 4 + rr][ln] = acc[t][ms][rr];
        __syncthreads();
        for (int idx = tid; idx < 512; idx += 320) {
            int mm = idx >> 4, n = idx & 15;
            int gm = half * 32 + mm;
            int jj = s * 64 + t * 16 + n;      // 0..319
            bool ok = jj < NH;
            float pi = tile[0][mm][n] + (ok ? b_iou[jj] : 0.f);
            float po = tile[1][mm][n] + (ok ? b_iou[NH + jj] : 0.f);
            float pu = tile[2][mm][n] + (ok ? b_iou[2 * NH + jj] : 0.f);
            float bj = ok ? b_f[jj] : 0.f;
            float fl = sigmoidf_(tile[3][mm][n] + bj);
            float fr = sigmoidf_(tile[4][mm][n] + bj);
            float cl = ok ? C[((size_t)l * NB + gm) * NH + jj] : 0.f;
            float cr = ok ? C[((size_t)r * NB + gm) * NH + jj] : 0.f;
            float cc = sigmoidf_(pi) * tanhf(pu) + fl * cl + fr * cr;
            float hh = sigmoidf_(po) * tanhf(cc);
            if (ok) C[((size_t)p * NB + gm) * NH + jj] = cc;
            HbfT[((size_t)p * 10 + (jj >> 5)) * TS + swz(gm, jj & 31)]
                = ok ? f2bf(hh) : (unsigned short)0;
        }
    }
}

// ---------------- leaf level: 3 waves (i,o,u only), 32-row half -------------
__global__ __launch_bounds__(192) void leaf_kernel(
    const unsigned short* __restrict__ AembT, const unsigned short* __restrict__ BW,
    const float* __restrict__ b_iou,
    unsigned short* __restrict__ HbfT, float* __restrict__ C, int m)
{
    int bid = blockIdx.x;
    int xcd = bid & 7, idx = bid >> 3;
    int o = idx % m, rest = idx / m;
    int p = 127 + xcd * m + o;
    int s = rest % 5, half = rest / 5;
    int tid = threadIdx.x;
    int w = tid >> 6, lane = tid & 63, ln = lane & 15, quad = lane >> 4;
    int g = (quad ^ ((ln >> 1) & 3)) * 8;
    int offA = (half * 32 + ln) * 32 + g;
    int offB = ln * 32 + g;

    const unsigned short* Bsrc = BW + (size_t)(w * 5 + s) * 17 * TS;
    const unsigned short* Ae = AembT + (size_t)p * 7 * TS;

    f32x4 acc[4][2];
#pragma unroll
    for (int t = 0; t < 4; ++t)
#pragma unroll
        for (int q = 0; q < 2; ++q) acc[t][q] = (f32x4){0.f, 0.f, 0.f, 0.f};

    gemm_h<7>(acc, Ae, Bsrc, offA, offB);

    __shared__ float tile[3][32][17];
    for (int t = 0; t < 4; ++t) {
        __syncthreads();
#pragma unroll
        for (int ms = 0; ms < 2; ++ms)
#pragma unroll
            for (int rr = 0; rr < 4; ++rr)
                tile[w][ms * 16 + quad * 4 + rr][ln] = acc[t][ms][rr];
        __syncthreads();
        for (int idx2 = tid; idx2 < 512; idx2 += 192) {
            int mm = idx2 >> 4, n = idx2 & 15;
            int gm = half * 32 + mm;
            int jj = s * 64 + t * 16 + n;
            bool ok = jj < NH;
            float pi = tile[0][mm][n] + (ok ? b_iou[jj] : 0.f);
            float po = tile[1][mm][n] + (ok ? b_iou[NH + jj] : 0.f);
            float pu = tile[2][mm][n] + (ok ? b_iou[2 * NH + jj] : 0.f);
            float cc = sigmoidf_(pi) * tanhf(pu);
            float hh = sigmoidf_(po) * tanhf(cc);
            if (ok) C[((size_t)p * NB + gm) * NH + jj] = cc;
            HbfT[((size_t)p * 10 + (jj >> 5)) * TS + swz(gm, jj & 31)]
                = ok ? f2bf(hh) : (unsigned short)0;
        }
    }
}

// ---------------- root -> logits -> log_softmax -----------------------------
__global__ __launch_bounds__(64) void out_kernel(
    const unsigned short* __restrict__ HbfT,
    const float* __restrict__ W_out, const float* __restrict__ b_out,
    float* __restrict__ out)
{
    int b = threadIdx.x;
    float l0 = 0.f, l1 = 0.f;
#pragma unroll 4
    for (int k = 0; k < NH; ++k) {
        float hk = bf2f(HbfT[(size_t)(k >> 5) * TS + swz(b, k & 31)]);
        l0 += hk * W_out[k * 2];
        l1 += hk * W_out[k * 2 + 1];
    }
    l0 += b_out[0];
    l1 += b_out[1];
    float m = fmaxf(l0, l1);
    float lse = m + logf(__expf(l0 - m) + __expf(l1 - m));
    out[b * 2 + 0] = l0 - lse;
    out[b * 2 + 1] = l1 - lse;
}

extern "C" void kernel_launch(void* const* d_in, const int* in_sizes, int n_in,
                              void* d_out, int out_size, void* d_ws, size_t ws_size,
                              hipStream_t stream)
{
    const int*   x     = (const int*)d_in[0];
    const float* embed = (const float*)d_in[3];
    const float* W_iou = (const float*)d_in[4];
    const float* U_iou = (const float*)d_in[5];
    const float* b_iou = (const float*)d_in[6];
    const float* W_f   = (const float*)d_in[7];
    const float* U_f   = (const float*)d_in[8];
    const float* b_f   = (const float*)d_in[9];
    const float* W_out = (const float*)d_in[10];
    const float* b_out = (const float*)d_in[11];

    char* ws = (char*)d_ws;
    unsigned short* HbfT  = (unsigned short*)(ws + 0);
    float*          C     = (float*)(ws + 10444800);
    unsigned short* AembT = (unsigned short*)(ws + 30028800);
    unsigned short* BW    = (unsigned short*)(ws + 37340160);

    prep_kernel<<<4096, 256, 0, stream>>>(U_iou, U_f, W_iou, W_f, embed, x, BW, AembT);

    // leaf: 128 nodes x 5 strips x 2 halves, 3 waves each
    leaf_kernel<<<1280, 192, 0, stream>>>(AembT, BW, b_iou, HbfT, C, 16);
    // internal levels 6..3: 80*m blocks (m nodes per XCD)
    for (int d = 6; d >= 3; --d) {
        int base = (1 << d) - 1;
        int m = 1 << (d - 3);
        level_kernel<<<80 * m, 320, 0, stream>>>(AembT, BW, b_iou, b_f, HbfT, C,
                                                 base, m, 0);
    }
    // levels 2..0: 80 blocks, xcd-gated
    for (int d = 2; d >= 0; --d) {
        level_kernel<<<80, 320, 0, stream>>>(AembT, BW, b_iou, b_f, HbfT, C,
                                             (1 << d) - 1, 0, 3 - d);
    }
    out_kernel<<<1, 64, 0, stream>>>(HbfT, W_out, b_out, (float*)d_out);
}